// Round 3
// baseline (235.793 us; speedup 1.0000x reference)
//
#include <hip/hip_runtime.h>
#include <hip/hip_bf16.h>

// Workspace layout (needs 34 MB):
//   [0, 2MB)    Ut : U^T as bf16, Ut[n][k] = bf16(U[k][n])
//   [2MB, 34MB) xg : gathered x as bf16, xg[b][i] = bf16(x[b][ans[b][i]])
#define WS_UT    ((size_t)0)
#define WS_XG    ((size_t)2*1024*1024)

typedef __attribute__((ext_vector_type(8))) short short8;
typedef __attribute__((ext_vector_type(4))) float floatx4;

__device__ __forceinline__ void load_lds16(const void* g, void* l) {
  __builtin_amdgcn_global_load_lds(
      (const __attribute__((address_space(1))) void*)g,
      (__attribute__((address_space(3))) void*)l, 16, 0, 0);
}

__device__ __forceinline__ unsigned short f2bf(float f) {
  __hip_bfloat16 h = __float2bfloat16(f);
  return __builtin_bit_cast(unsigned short, h);
}

// ---------------- K1: prep (Ut = bf16(U^T)) + gather (xg) in one launch ----------------
// blocks [0,256): transpose+cast U.  blocks [256, 256+4096): per-row gather of x.
__global__ void __launch_bounds__(256) prep_gather_k(const float* __restrict__ U,
                                                     const float* __restrict__ x,
                                                     const int* __restrict__ perm,
                                                     const int* __restrict__ prand,
                                                     unsigned short* __restrict__ ut,
                                                     unsigned short* __restrict__ xg) {
  __shared__ __align__(16) char smem[64 * 65 * 4];  // union: tile[64][65] f32 / xrow[4][1024] f32
  if (blockIdx.x < 256) {
    float (*tile)[65] = (float (*)[65])smem;
    const int tn = (blockIdx.x & 15) * 64;
    const int tk = (blockIdx.x >> 4) * 64;
    const int r = threadIdx.x >> 6;
    const int c = threadIdx.x & 63;
    for (int s = 0; s < 16; ++s)
      tile[s * 4 + r][c] = U[(size_t)(tk + s * 4 + r) * 1024 + tn + c];
    __syncthreads();
    for (int s = 0; s < 16; ++s)
      ut[(size_t)(tn + s * 4 + r) * 1024 + tk + c] = f2bf(tile[c][s * 4 + r]);
    return;
  }
  float (*xrow)[1024] = (float (*)[1024])smem;
  const int w = threadIdx.x >> 6, lane = threadIdx.x & 63;
  const int row = (blockIdx.x - 256) * 4 + w;
  const unsigned mult = ((unsigned)prand[0] * 6u) & 1023u;
  const unsigned br = (((unsigned)row & 1023u) * mult + 1u) & 1023u;
  const float* xr = x + (size_t)row * 1024;
  unsigned short* xo = xg + (size_t)row * 1024;
  for (int t = 0; t < 4; ++t) {
    floatx4 v = *(const floatx4*)(xr + t * 256 + lane * 4);
    *(floatx4*)(&xrow[w][t * 256 + lane * 4]) = v;
  }
  __syncthreads();
  for (int t = 0; t < 4; ++t) {
    int i0 = t * 256 + lane * 4;
    int4 p = *(const int4*)(perm + i0);
    ushort4 o;
    o.x = f2bf(xrow[w][((unsigned)p.x * br) & 1023u]);
    o.y = f2bf(xrow[w][((unsigned)p.y * br) & 1023u]);
    o.z = f2bf(xrow[w][((unsigned)p.z * br) & 1023u]);
    o.w = f2bf(xrow[w][((unsigned)p.w * br) & 1023u]);
    *(ushort4*)(xo + i0) = o;
  }
}

// ---------------- K2: GEMM (y = xg @ U) with fused scatter epilogue ----------------
// out[row][ans(col)] = acc/3 + x[row][ans(col)]  -- residual read at the TARGET index,
// so the epilogue is a scattered read-modify-write; no y buffer, no scatter pass.
// XCD swizzle keeps all 8 bn-blocks of one bm panel on one XCD -> x/out lines merge in L2.
__global__ void __launch_bounds__(256) gemm_scatter_k(const unsigned short* __restrict__ xg,
                                                      const unsigned short* __restrict__ ut,
                                                      const float* __restrict__ x,
                                                      const int* __restrict__ perm,
                                                      const int* __restrict__ prand,
                                                      float* __restrict__ out) {
  __shared__ __align__(16) char ldsA[16384];  // 128 rows x 64 bf16, XOR-swizzled 16B chunks
  __shared__ __align__(16) char ldsB[16384];
  const int tid = threadIdx.x;
  const int w = tid >> 6, lane = tid & 63;
  const int l = blockIdx.x;
  const int xcd = l & 7;
  const int j = l >> 3;
  const int bn = (j & 7) * 128;
  const int bm = ((j >> 3) * 8 + xcd) * 128;
  const int wm = (w & 1) * 64, wn = (w >> 1) * 64;
  const int m = lane & 15, q = lane >> 4;
  const int srow = lane >> 3;
  const int sch = lane & 7;

  floatx4 acc[4][4];
  for (int i = 0; i < 4; ++i)
    for (int jj = 0; jj < 4; ++jj) acc[i][jj] = (floatx4)0.0f;

  for (int kt = 0; kt < 16; ++kt) {
    const int k0 = kt * 64;
    for (int t = 0; t < 4; ++t) {
      int row = w * 32 + t * 8 + srow;
      int sc = sch ^ (row & 7);
      load_lds16(xg + ((size_t)(bm + row) * 1024 + k0 + sc * 8),
                 ldsA + row * 128 + sch * 16);
      load_lds16(ut + ((size_t)(bn + row) * 1024 + k0 + sc * 8),
                 ldsB + row * 128 + sch * 16);
    }
    __syncthreads();
    for (int s = 0; s < 2; ++s) {
      short8 af[4], bfr[4];
      const int swz = ((s * 4 + q) ^ (m & 7)) * 16;
      for (int i = 0; i < 4; ++i)
        af[i] = *(const short8*)(ldsA + (wm + i * 16 + m) * 128 + swz);
      for (int jj = 0; jj < 4; ++jj)
        bfr[jj] = *(const short8*)(ldsB + (wn + jj * 16 + m) * 128 + swz);
      for (int i = 0; i < 4; ++i)
        for (int jj = 0; jj < 4; ++jj)
          acc[i][jj] = __builtin_amdgcn_mfma_f32_16x16x32_bf16(af[i], bfr[jj], acc[i][jj], 0, 0, 0);
    }
    __syncthreads();
  }

  // fused epilogue: C/D layout col = lane&15, row = q*4 + reg
  const unsigned mult = ((unsigned)prand[0] * 6u) & 1023u;
  unsigned pcol[4];
  for (int jj = 0; jj < 4; ++jj)
    pcol[jj] = (unsigned)perm[bn + wn + jj * 16 + m];
  for (int i = 0; i < 4; ++i) {
    const int rowb = bm + wm + i * 16 + q * 4;
    for (int r = 0; r < 4; ++r) {
      const int row = rowb + r;
      const unsigned br = (((unsigned)row & 1023u) * mult + 1u) & 1023u;
      const float* xr = x + (size_t)row * 1024;
      float* orow = out + (size_t)row * 1024;
      for (int jj = 0; jj < 4; ++jj) {
        const unsigned tc = (pcol[jj] * br) & 1023u;
        orow[tc] = 0.3333333333333333f * acc[i][jj][r] + xr[tc];
      }
    }
  }
}

extern "C" void kernel_launch(void* const* d_in, const int* in_sizes, int n_in,
                              void* d_out, int out_size, void* d_ws, size_t ws_size,
                              hipStream_t stream) {
  const float* x = (const float*)d_in[0];
  const float* U = (const float*)d_in[1];
  const int* perm = (const int*)d_in[2];
  const int* prand = (const int*)d_in[3];
  float* out = (float*)d_out;
  char* ws = (char*)d_ws;
  unsigned short* ut = (unsigned short*)(ws + WS_UT);
  unsigned short* xg = (unsigned short*)(ws + WS_XG);

  prep_gather_k<<<256 + 4096, 256, 0, stream>>>(U, x, perm, prand, ut, xg);
  gemm_scatter_k<<<1024, 256, 0, stream>>>(xg, ut, x, perm, prand, out);
}

// Round 4
// 167.929 us; speedup vs baseline: 1.4041x; 1.4041x over previous
//
#include <hip/hip_runtime.h>
#include <hip/hip_bf16.h>

// Workspace layout (needs 66 MB):
//   [0, 2MB)    Ut : U^T as bf16, Ut[n][k] = bf16(U[k][n])
//   [2MB, 34MB) xg : gathered x as bf16, xg[b][i] = bf16(x[b][ans[b][i]])
//   [34MB,66MB) y  : GEMM result, bf16
#define WS_UT    ((size_t)0)
#define WS_XG    ((size_t)2*1024*1024)
#define WS_Y     ((size_t)34*1024*1024)

typedef __attribute__((ext_vector_type(8))) short short8;
typedef __attribute__((ext_vector_type(4))) float floatx4;

__device__ __forceinline__ void load_lds16(const void* g, void* l) {
  __builtin_amdgcn_global_load_lds(
      (const __attribute__((address_space(1))) void*)g,
      (__attribute__((address_space(3))) void*)l, 16, 0, 0);
}

__device__ __forceinline__ unsigned short f2bf(float f) {
  __hip_bfloat16 h = __float2bfloat16(f);
  return __builtin_bit_cast(unsigned short, h);
}
__device__ __forceinline__ float bf2f(unsigned short u) {
  return __uint_as_float(((unsigned)u) << 16);
}

// ---------------- K1: prep (Ut = bf16(U^T)) + gather (xg) in one launch ----------------
// blocks [0,256): transpose+cast U.  blocks [256, 256+4096): per-row LDS gather of x.
__global__ void __launch_bounds__(256) prep_gather_k(const float* __restrict__ U,
                                                     const float* __restrict__ x,
                                                     const int* __restrict__ perm,
                                                     const int* __restrict__ prand,
                                                     unsigned short* __restrict__ ut,
                                                     unsigned short* __restrict__ xg) {
  __shared__ __align__(16) char smem[64 * 65 * 4];  // union: tile[64][65] f32 / xrow[4][1024] f32
  if (blockIdx.x < 256) {
    float (*tile)[65] = (float (*)[65])smem;
    const int tn = (blockIdx.x & 15) * 64;
    const int tk = (blockIdx.x >> 4) * 64;
    const int r = threadIdx.x >> 6;
    const int c = threadIdx.x & 63;
    for (int s = 0; s < 16; ++s)
      tile[s * 4 + r][c] = U[(size_t)(tk + s * 4 + r) * 1024 + tn + c];
    __syncthreads();
    for (int s = 0; s < 16; ++s)
      ut[(size_t)(tn + s * 4 + r) * 1024 + tk + c] = f2bf(tile[c][s * 4 + r]);
    return;
  }
  float (*xrow)[1024] = (float (*)[1024])smem;
  const int w = threadIdx.x >> 6, lane = threadIdx.x & 63;
  const int row = (blockIdx.x - 256) * 4 + w;
  const unsigned mult = ((unsigned)prand[0] * 6u) & 1023u;
  const unsigned br = (((unsigned)row & 1023u) * mult + 1u) & 1023u;
  const float* xr = x + (size_t)row * 1024;
  unsigned short* xo = xg + (size_t)row * 1024;
  for (int t = 0; t < 4; ++t) {
    floatx4 v = *(const floatx4*)(xr + t * 256 + lane * 4);
    *(floatx4*)(&xrow[w][t * 256 + lane * 4]) = v;
  }
  __syncthreads();
  for (int t = 0; t < 4; ++t) {
    int i0 = t * 256 + lane * 4;
    int4 p = *(const int4*)(perm + i0);
    ushort4 o;
    o.x = f2bf(xrow[w][((unsigned)p.x * br) & 1023u]);
    o.y = f2bf(xrow[w][((unsigned)p.y * br) & 1023u]);
    o.z = f2bf(xrow[w][((unsigned)p.z * br) & 1023u]);
    o.w = f2bf(xrow[w][((unsigned)p.w * br) & 1023u]);
    *(ushort4*)(xo + i0) = o;
  }
}

// ---------------- K2: GEMM y = xg @ U, 256x128 tile, BK=64 ----------------
// 64 MFMA per barrier (2x the 128x128 tile) to amortize the structural
// s_waitcnt-vmcnt(0)+s_barrier drain. XCD swizzle: all 8 bn-blocks of one
// bm panel on one XCD -> each A panel fetched into its L2 once.
__global__ void __launch_bounds__(256, 2) gemm_k(const unsigned short* __restrict__ xg,
                                                 const unsigned short* __restrict__ ut,
                                                 unsigned short* __restrict__ y) {
  __shared__ __align__(16) char ldsA[32768];  // 256 rows x 64 bf16, XOR-swizzled 16B chunks
  __shared__ __align__(16) char ldsB[16384];  // 128 rows x 64 bf16
  const int tid = threadIdx.x;
  const int w = tid >> 6, lane = tid & 63;
  const int l = blockIdx.x;
  const int xcd = l & 7;
  const int j = l >> 3;
  const int bn = (j & 7) * 128;
  const int bm = ((j >> 3) * 8 + xcd) * 256;
  const int wm = (w & 1) * 128, wn = (w >> 1) * 64;
  const int m = lane & 15, q = lane >> 4;
  const int srow = lane >> 3;   // staging: 8 rows / instr
  const int sch = lane & 7;     // staging: 16B chunk 0..7

  floatx4 acc[8][4];
  for (int i = 0; i < 8; ++i)
    for (int jj = 0; jj < 4; ++jj) acc[i][jj] = (floatx4)0.0f;

  for (int kt = 0; kt < 16; ++kt) {
    const int k0 = kt * 64;
    // A: 256 rows, each wave stages 64 rows (8 instr/lane)
    for (int t = 0; t < 8; ++t) {
      int row = w * 64 + t * 8 + srow;
      int sc = sch ^ (row & 7);
      load_lds16(xg + ((size_t)(bm + row) * 1024 + k0 + sc * 8),
                 ldsA + row * 128 + sch * 16);
    }
    // B: 128 rows, each wave stages 32 rows (4 instr/lane)
    for (int t = 0; t < 4; ++t) {
      int row = w * 32 + t * 8 + srow;
      int sc = sch ^ (row & 7);
      load_lds16(ut + ((size_t)(bn + row) * 1024 + k0 + sc * 8),
                 ldsB + row * 128 + sch * 16);
    }
    __syncthreads();
    for (int s = 0; s < 2; ++s) {
      short8 af[8], bfr[4];
      const int swz = ((s * 4 + q) ^ (m & 7)) * 16;
      for (int i = 0; i < 8; ++i)
        af[i] = *(const short8*)(ldsA + (wm + i * 16 + m) * 128 + swz);
      for (int jj = 0; jj < 4; ++jj)
        bfr[jj] = *(const short8*)(ldsB + (wn + jj * 16 + m) * 128 + swz);
      for (int i = 0; i < 8; ++i)
        for (int jj = 0; jj < 4; ++jj)
          acc[i][jj] = __builtin_amdgcn_mfma_f32_16x16x32_bf16(af[i], bfr[jj], acc[i][jj], 0, 0, 0);
    }
    __syncthreads();
  }
  // epilogue: C/D layout col=lane&15, row=quad*4+reg
  for (int i = 0; i < 8; ++i) {
    int row = bm + wm + i * 16 + q * 4;
    for (int jj = 0; jj < 4; ++jj) {
      int col = bn + wn + jj * 16 + m;
      for (int r = 0; r < 4; ++r)
        y[(size_t)(row + r) * 1024 + col] = f2bf(acc[i][jj][r]);
    }
  }
}

// ---------------- K3: out[b][ans[j]] = (1/3)*y[b][j] + xg[b][j] ----------------
// Iterate j coalesced; scatter into wave-private LDS row; store coalesced.
__global__ void __launch_bounds__(256) scatter_out_k(const unsigned short* __restrict__ xg,
                                                     const unsigned short* __restrict__ y,
                                                     const int* __restrict__ perm,
                                                     const int* __restrict__ prand,
                                                     float* __restrict__ out) {
  __shared__ float obuf[4][1024];   // 16 KB, wave-private rows
  const int w = threadIdx.x >> 6, lane = threadIdx.x & 63;
  const int row = blockIdx.x * 4 + w;
  const unsigned mult = ((unsigned)prand[0] * 6u) & 1023u;
  const unsigned br = (((unsigned)row & 1023u) * mult + 1u) & 1023u;
  const unsigned short* yr = y + (size_t)row * 1024;
  const unsigned short* xr = xg + (size_t)row * 1024;
  for (int t = 0; t < 4; ++t) {
    int i0 = t * 256 + lane * 4;
    int4 p = *(const int4*)(perm + i0);
    ushort4 yv = *(const ushort4*)(yr + i0);
    ushort4 xv = *(const ushort4*)(xr + i0);
    obuf[w][((unsigned)p.x * br) & 1023u] = 0.3333333333333333f * bf2f(yv.x) + bf2f(xv.x);
    obuf[w][((unsigned)p.y * br) & 1023u] = 0.3333333333333333f * bf2f(yv.y) + bf2f(xv.y);
    obuf[w][((unsigned)p.z * br) & 1023u] = 0.3333333333333333f * bf2f(yv.z) + bf2f(xv.z);
    obuf[w][((unsigned)p.w * br) & 1023u] = 0.3333333333333333f * bf2f(yv.w) + bf2f(xv.w);
  }
  __syncthreads();
  float* orow = out + (size_t)row * 1024;
  for (int t = 0; t < 4; ++t) {
    int c0 = t * 256 + lane * 4;
    *(floatx4*)(orow + c0) = *(const floatx4*)(&obuf[w][c0]);
  }
}

extern "C" void kernel_launch(void* const* d_in, const int* in_sizes, int n_in,
                              void* d_out, int out_size, void* d_ws, size_t ws_size,
                              hipStream_t stream) {
  const float* x = (const float*)d_in[0];
  const float* U = (const float*)d_in[1];
  const int* perm = (const int*)d_in[2];
  const int* prand = (const int*)d_in[3];
  float* out = (float*)d_out;
  char* ws = (char*)d_ws;
  unsigned short* ut = (unsigned short*)(ws + WS_UT);
  unsigned short* xg = (unsigned short*)(ws + WS_XG);
  unsigned short* y = (unsigned short*)(ws + WS_Y);

  prep_gather_k<<<256 + 4096, 256, 0, stream>>>(U, x, perm, prand, ut, xg);
  gemm_k<<<512, 256, 0, stream>>>(xg, ut, y);
  scatter_out_k<<<4096, 256, 0, stream>>>(xg, y, perm, prand, out);
}